// Round 3
// baseline (174.004 us; speedup 1.0000x reference)
//
#include <hip/hip_runtime.h>
#include <cstdint>

#define MDIM 2048
#define KDIM 1024
#define CDIM 8192
#define BM 128
#define BN 128
#define BK 32
#define NCHUNK (2 * (CDIM / BN))   // 128 partial chunks of 64 cols each

typedef __attribute__((ext_vector_type(8))) __bf16 bf16x8;
typedef __attribute__((ext_vector_type(4))) float f32x4;

// ---------- helpers ----------
__device__ __forceinline__ void async_ld16(const void* g, void* l) {
  __builtin_amdgcn_global_load_lds(
      (__attribute__((address_space(1))) void*)(g),
      (__attribute__((address_space(3))) void*)(l),
      16, 0, 0);
}

// ---------- K0: c2 = ||cent||^2 (fp32) ----------
__global__ __launch_bounds__(256) void c2_kernel(const float* __restrict__ cent,
                                                 float* __restrict__ c2) {
  const int row = blockIdx.x, t = threadIdx.x;
  const float4 v = ((const float4*)(cent + (size_t)row * KDIM))[t];
  float p = v.x * v.x + v.y * v.y + v.z * v.z + v.w * v.w;
  for (int d = 32; d; d >>= 1) p += __shfl_down(p, d, 64);
  __shared__ float red[4];
  if ((t & 63) == 0) red[t >> 6] = p;
  __syncthreads();
  if (t == 0) c2[row] = red[0] + red[1] + red[2] + red[3];
}

// ---------- K1: fp32-direct MFMA GEMM (s = 2*x.c - c2) + fused per-64col softmax/argmax ----------
// Stages fp32 tiles to LDS via global_load_lds (16B granules). Granule column is
// XOR-swizzled by (row&7) at stage time: a 128B fp32 row spans all 32 banks, so
// unswizzled fragment reads would be 16-way conflicted; swizzle spreads the 8
// granules across all 8 bank-quads (8-way, same as the bf16 layout had).
__global__ __launch_bounds__(256) void gemm_reduce(
    const float* __restrict__ A,      // x, (MDIM,KDIM) fp32
    const float* __restrict__ Bf,     // centroids, (CDIM,KDIM) fp32
    const float* __restrict__ c2,
    float* __restrict__ pm, float* __restrict__ pl, int* __restrict__ pidx) {
  __shared__ __align__(16) float As[BM * BK];   // 16 KB
  __shared__ __align__(16) float Bs[BN * BK];   // 16 KB
  const int tid = threadIdx.x;
  const int wave = tid >> 6, lane = tid & 63;
  const int wm = wave >> 1, wn = wave & 1;
  const int bn = blockIdx.x, bm = blockIdx.y;
  const int quad = lane >> 4, c16 = lane & 15;

  f32x4 acc[4][4] = {};

  // staging: lane -> row-in-8-group = lane>>3, granule = (lane&7) XOR (row&7)
  const int srow8 = lane >> 3;
  const int sg = (lane & 7) ^ srow8;           // swizzled 16B-granule column
  const float* agb = A + (size_t)(bm * BM + wave * 32 + srow8) * KDIM + sg * 4;
  const float* bgb = Bf + (size_t)(bn * BN + wave * 32 + srow8) * KDIM + sg * 4;

  for (int k0 = 0; k0 < KDIM; k0 += BK) {
#pragma unroll
    for (int g = 0; g < 4; ++g) {
      async_ld16(agb + (size_t)(g * 8) * KDIM + k0, &As[(wave * 32 + g * 8) * BK]);
      async_ld16(bgb + (size_t)(g * 8) * KDIM + k0, &Bs[(wave * 32 + g * 8) * BK]);
    }
    __syncthreads();   // drains vmcnt -> LDS valid

    bf16x8 a[4], b[4];
#pragma unroll
    for (int mt = 0; mt < 4; ++mt) {
      const int r = wm * 64 + mt * 16 + c16;
      const int s = c16 & 7;
      const float4 f0 = *(const float4*)&As[r * BK + (((quad * 2) ^ s) * 4)];
      const float4 f1 = *(const float4*)&As[r * BK + (((quad * 2 + 1) ^ s) * 4)];
      a[mt][0] = (__bf16)f0.x; a[mt][1] = (__bf16)f0.y;
      a[mt][2] = (__bf16)f0.z; a[mt][3] = (__bf16)f0.w;
      a[mt][4] = (__bf16)f1.x; a[mt][5] = (__bf16)f1.y;
      a[mt][6] = (__bf16)f1.z; a[mt][7] = (__bf16)f1.w;
    }
#pragma unroll
    for (int nt = 0; nt < 4; ++nt) {
      const int r = wn * 64 + nt * 16 + c16;
      const int s = c16 & 7;
      const float4 f0 = *(const float4*)&Bs[r * BK + (((quad * 2) ^ s) * 4)];
      const float4 f1 = *(const float4*)&Bs[r * BK + (((quad * 2 + 1) ^ s) * 4)];
      b[nt][0] = (__bf16)f0.x; b[nt][1] = (__bf16)f0.y;
      b[nt][2] = (__bf16)f0.z; b[nt][3] = (__bf16)f0.w;
      b[nt][4] = (__bf16)f1.x; b[nt][5] = (__bf16)f1.y;
      b[nt][6] = (__bf16)f1.z; b[nt][7] = (__bf16)f1.w;
    }
#pragma unroll
    for (int mt = 0; mt < 4; ++mt)
#pragma unroll
      for (int nt = 0; nt < 4; ++nt)
        acc[mt][nt] = __builtin_amdgcn_mfma_f32_16x16x32_bf16(a[mt], b[nt], acc[mt][nt], 0, 0, 0);
    __syncthreads();
  }

  // Epilogue: C/D layout: col = lane&15, row = quad*4 + reg.
  const int colbase = bn * BN + wn * 64;
  float c2v[4];
#pragma unroll
  for (int nt = 0; nt < 4; ++nt) c2v[nt] = c2[colbase + nt * 16 + c16];

  const int chunk = bn * 2 + wn;
#pragma unroll
  for (int mt = 0; mt < 4; ++mt) {
#pragma unroll
    for (int r = 0; r < 4; ++r) {
      float sv[4];
#pragma unroll
      for (int nt = 0; nt < 4; ++nt) sv[nt] = 2.0f * acc[mt][nt][r] - c2v[nt];
      float m = sv[0];
      int idx = colbase + c16;
#pragma unroll
      for (int nt = 1; nt < 4; ++nt) {
        if (sv[nt] > m) { m = sv[nt]; idx = colbase + nt * 16 + c16; }
      }
      float l = 0.f;
#pragma unroll
      for (int nt = 0; nt < 4; ++nt) l += __expf(sv[nt] - m);
      for (int d = 1; d < 16; d <<= 1) {
        float om = __shfl_xor(m, d, 64);
        float ol = __shfl_xor(l, d, 64);
        int oi = __shfl_xor(idx, d, 64);
        float M = fmaxf(m, om);
        l = l * __expf(m - M) + ol * __expf(om - M);
        idx = (om > m || (om == m && oi < idx)) ? oi : idx;
        m = M;
      }
      if (c16 == 0) {
        const int row = bm * BM + wm * 64 + mt * 16 + quad * 4 + r;
        pm[(size_t)row * NCHUNK + chunk] = m;     // row-major for coalesced combine
        pl[(size_t)row * NCHUNK + chunk] = l;
        pidx[(size_t)row * NCHUNK + chunk] = idx;
      }
    }
  }
}

// ---------- K2: per-row combine (128 threads = 128 chunks) + fused sy dot ----------
__global__ __launch_bounds__(128) void combine_kernel(
    const float* __restrict__ pm, const float* __restrict__ pl,
    const int* __restrict__ pidx, const float* __restrict__ x,
    const float* __restrict__ cent, const float* __restrict__ c2,
    const int* __restrict__ y,
    float* __restrict__ loss_part, float* __restrict__ corr_part) {
  const int row = blockIdx.x, t = threadIdx.x;  // t = chunk id, 0..127
  const int yc = y[row];

  float m = pm[(size_t)row * NCHUNK + t];
  float l = pl[(size_t)row * NCHUNK + t];
  int idx = pidx[(size_t)row * NCHUNK + t];

  const float4* xa = (const float4*)(x + (size_t)row * KDIM) + t * 2;
  const float4* ca = (const float4*)(cent + (size_t)yc * KDIM) + t * 2;
  const float4 a0 = xa[0], a1 = xa[1], b0 = ca[0], b1 = ca[1];
  float dot = a0.x * b0.x + a0.y * b0.y + a0.z * b0.z + a0.w * b0.w
            + a1.x * b1.x + a1.y * b1.y + a1.z * b1.z + a1.w * b1.w;

  for (int d = 1; d < 64; d <<= 1) {
    const float om = __shfl_xor(m, d, 64);
    const float ol = __shfl_xor(l, d, 64);
    const int oi = __shfl_xor(idx, d, 64);
    const float od = __shfl_xor(dot, d, 64);
    const float M = fmaxf(m, om);
    l = l * __expf(m - M) + ol * __expf(om - M);
    idx = (om > m || (om == m && oi < idx)) ? oi : idx;
    m = M;
    dot += od;
  }
  __shared__ float sm[2], sl[2], sd[2];
  __shared__ int si[2];
  if ((t & 63) == 0) { sm[t >> 6] = m; sl[t >> 6] = l; si[t >> 6] = idx; sd[t >> 6] = dot; }
  __syncthreads();
  if (t == 0) {
    const float m0 = sm[0], m1 = sm[1];
    const float M = fmaxf(m0, m1);
    const float L = sl[0] * __expf(m0 - M) + sl[1] * __expf(m1 - M);
    int g;
    if (m1 > m0 || (m1 == m0 && si[1] < si[0])) g = si[1]; else g = si[0];
    const float sy = 2.0f * (sd[0] + sd[1]) - c2[yc];
    loss_part[row] = __logf(L) + M - sy;
    corr_part[row] = (g == yc) ? 1.f : 0.f;
  }
}

// ---------- K3: finalize means ----------
__global__ __launch_bounds__(256) void finalize(const float* __restrict__ loss_part,
                                                const float* __restrict__ corr_part,
                                                float* __restrict__ out) {
  const int t = threadIdx.x;
  float s0 = 0.f, s1 = 0.f;
  for (int i = t; i < MDIM; i += 256) { s0 += loss_part[i]; s1 += corr_part[i]; }
  for (int d = 32; d; d >>= 1) {
    s0 += __shfl_down(s0, d, 64);
    s1 += __shfl_down(s1, d, 64);
  }
  __shared__ float r0[4], r1[4];
  if ((t & 63) == 0) { r0[t >> 6] = s0; r1[t >> 6] = s1; }
  __syncthreads();
  if (t == 0) {
    out[0] = (r0[0] + r0[1] + r0[2] + r0[3]) * (1.0f / MDIM);
    out[1] = (r1[0] + r1[1] + r1[2] + r1[3]) * (1.0f / MDIM);
  }
}

// ---------- launch ----------
extern "C" void kernel_launch(void* const* d_in, const int* in_sizes, int n_in,
                              void* d_out, int out_size, void* d_ws, size_t ws_size,
                              hipStream_t stream) {
  const float* x = (const float*)d_in[0];
  const int* y = (const int*)d_in[1];
  const float* cent = (const float*)d_in[2];
  float* out = (float*)d_out;

  char* ws = (char*)d_ws;
  const size_t OFF_C2 = 0;                                   // 32 KB
  const size_t OFF_PM = OFF_C2 + (size_t)CDIM * 4;           // 1 MB
  const size_t OFF_PL = OFF_PM + (size_t)NCHUNK * MDIM * 4;  // 1 MB
  const size_t OFF_PI = OFF_PL + (size_t)NCHUNK * MDIM * 4;  // 1 MB
  const size_t OFF_LP = OFF_PI + (size_t)NCHUNK * MDIM * 4;  // 8 KB
  const size_t OFF_CP = OFF_LP + (size_t)MDIM * 4;           // 8 KB
  const size_t NEED = OFF_CP + (size_t)MDIM * 4;
  if (ws_size < NEED) return;

  float* c2 = (float*)(ws + OFF_C2);
  float* pm = (float*)(ws + OFF_PM);
  float* pl = (float*)(ws + OFF_PL);
  int* pidx = (int*)(ws + OFF_PI);
  float* loss_part = (float*)(ws + OFF_LP);
  float* corr_part = (float*)(ws + OFF_CP);

  c2_kernel<<<CDIM, 256, 0, stream>>>(cent, c2);
  gemm_reduce<<<dim3(CDIM / BN, MDIM / BM), 256, 0, stream>>>(x, cent, c2, pm, pl, pidx);
  combine_kernel<<<MDIM, 128, 0, stream>>>(pm, pl, pidx, x, cent, c2, y, loss_part, corr_part);
  finalize<<<1, 256, 0, stream>>>(loss_part, corr_part, out);
}